// Round 17
// baseline (855.232 us; speedup 1.0000x reference)
//
#include <hip/hip_runtime.h>
#include <hip/hip_bf16.h>
#include <math.h>

typedef unsigned short u16;
typedef __bf16 bf16x8 __attribute__((ext_vector_type(8)));
typedef float floatx4 __attribute__((ext_vector_type(4)));

#define LORA_SCALING 2.0f   // alpha 32 / rank 16

// R15 pipeline kept verbatim (correct, 707us). THIS ROUND adds 3 ablation
// dispatches (results to scratch) to decompose the invariant ~285us GEMM:
// ABL1 = K-loop w/o epilogue; ABL2 = staging-only; ABL3 = compute-only.

// counted waits + raw barrier (T4): never drain vmcnt in the main loop.
#define VMWAIT(n) asm volatile("s_waitcnt vmcnt(" #n ")" ::: "memory")
#define BARRIER() asm volatile("s_barrier" ::: "memory")

// ---------- helpers ----------
__device__ __forceinline__ u16 f2bf(float f) {
  unsigned u = __float_as_uint(f);
  u += 0x7fffu + ((u >> 16) & 1u);   // round-to-nearest-even
  return (u16)(u >> 16);
}
__device__ __forceinline__ float bflo(unsigned u) { return __uint_as_float(u << 16); }
__device__ __forceinline__ float bfhi(unsigned u) { return __uint_as_float(u & 0xffff0000u); }

// ---------- zero amax slots (ws poisoned 0xAA each launch) ----------
__global__ void zero_kernel(unsigned* amax) {
  if (threadIdx.x < 2) amax[threadIdx.x] = 0u;
}

// ---------- fused absmax of both weight tensors ----------
__global__ void absmax2_kernel(const float* __restrict__ wa, const float* __restrict__ wb,
                               long long n4, unsigned* __restrict__ out) {
  int which = blockIdx.x & 1;
  const float* w = which ? wb : wa;
  long long i = (long long)(blockIdx.x >> 1) * blockDim.x + threadIdx.x;
  long long stride = (long long)(gridDim.x >> 1) * blockDim.x;
  float m = 0.f;
  for (; i < n4; i += stride) {
    float4 v = ((const float4*)w)[i];
    m = fmaxf(m, fmaxf(fmaxf(fabsf(v.x), fabsf(v.y)), fmaxf(fabsf(v.z), fabsf(v.w))));
  }
#pragma unroll
  for (int o = 32; o > 0; o >>= 1) m = fmaxf(m, __shfl_xor(m, o, 64));
  __shared__ float sm[4];
  int lane = threadIdx.x & 63, wv = threadIdx.x >> 6;
  if (lane == 0) sm[wv] = m;
  __syncthreads();
  if (threadIdx.x == 0) {
    float mm = fmaxf(fmaxf(sm[0], sm[1]), fmaxf(sm[2], sm[3]));
    atomicMax(out + which, __float_as_uint(mm));   // nonneg: uint order == float order
  }
}

// ---------- packing, dst-major with padded row stride ----------
__device__ __forceinline__ void pack_q(const float* __restrict__ w, u16* __restrict__ dst,
                                       long long d, int nkc, int kc3, float inv, float scale) {
  int l = (int)(d & 63);
  long long frag = d >> 6;
  long long mb = frag / nkc, kc = frag % nkc;
  long long m = mb * 16 + (l & 15);
  long long k8 = kc * 4 + (l >> 4);
  const float4* s = (const float4*)(w + ((m << kc3) + k8) * 8);
  float4 a = s[0], b = s[1];
  union { u16 h[8]; uint4 v; } o;
  o.h[0] = f2bf(fminf(fmaxf(rintf(a.x * inv), -128.f), 127.f) * scale);
  o.h[1] = f2bf(fminf(fmaxf(rintf(a.y * inv), -128.f), 127.f) * scale);
  o.h[2] = f2bf(fminf(fmaxf(rintf(a.z * inv), -128.f), 127.f) * scale);
  o.h[3] = f2bf(fminf(fmaxf(rintf(a.w * inv), -128.f), 127.f) * scale);
  o.h[4] = f2bf(fminf(fmaxf(rintf(b.x * inv), -128.f), 127.f) * scale);
  o.h[5] = f2bf(fminf(fmaxf(rintf(b.y * inv), -128.f), 127.f) * scale);
  o.h[6] = f2bf(fminf(fmaxf(rintf(b.z * inv), -128.f), 127.f) * scale);
  o.h[7] = f2bf(fminf(fmaxf(rintf(b.w * inv), -128.f), 127.f) * scale);
  ((uint4*)dst)[(mb * (nkc + 1) + kc) * 64 + l] = o.v;
}
__device__ __forceinline__ void pack_c(const float* __restrict__ x, u16* __restrict__ dst,
                                       long long d, int nkc, int kc3) {
  int l = (int)(d & 63);
  long long frag = d >> 6;
  long long mb = frag / nkc, kc = frag % nkc;
  long long m = mb * 16 + (l & 15);
  long long k8 = kc * 4 + (l >> 4);
  const float4* s = (const float4*)(x + ((m << kc3) + k8) * 8);
  float4 a = s[0], b = s[1];
  union { u16 h[8]; uint4 v; } o;
  o.h[0] = f2bf(a.x); o.h[1] = f2bf(a.y); o.h[2] = f2bf(a.z); o.h[3] = f2bf(a.w);
  o.h[4] = f2bf(b.x); o.h[5] = f2bf(b.y); o.h[6] = f2bf(b.z); o.h[7] = f2bf(b.w);
  ((uint4*)dst)[(mb * (nkc + 1) + kc) * 64 + l] = o.v;
}

__global__ void pack_all_kernel(const float* __restrict__ wfc, const float* __restrict__ wpr,
                                const float* __restrict__ x, const unsigned* __restrict__ amax,
                                u16* __restrict__ qfc, u16* __restrict__ qpr, u16* __restrict__ xb,
                                long long nfc, long long npr, long long nx, int kfc, int kpr, int kx) {
  float am0 = __uint_as_float(amax[0]);
  float am1 = __uint_as_float(amax[1]);
  float sc0 = am0 * (1.0f / 127.0f), in0 = 127.0f / am0;
  float sc1 = am1 * (1.0f / 127.0f), in1 = 127.0f / am1;
  long long i = (long long)blockIdx.x * blockDim.x + threadIdx.x;
  long long stride = (long long)gridDim.x * blockDim.x;
  long long tot = nfc + npr + nx;
  for (; i < tot; i += stride) {
    if (i < nfc)            pack_q(wfc, qfc, i, 1 << (kfc - 2), kfc, in0, sc0);
    else if (i < nfc + npr) pack_q(wpr, qpr, i - nfc, 1 << (kpr - 2), kpr, in1, sc1);
    else                    pack_c(x, xb, i - nfc - npr, 1 << (kx - 2), kx);
  }
}

// ---------- LoRA t = X(packed bf16) @ A^T(fp32): one wave per row, X read once ----------
__global__ void lora_t_kernel(const u16* __restrict__ X, const float* __restrict__ A,
                              float* __restrict__ T, int K) {
  int wv = threadIdx.x >> 6, lane = threadIdx.x & 63;
  long long row = (long long)blockIdx.x * 4 + wv;
  int nk = K >> 5;
  const u16* xp = X + ((row >> 4) * (long long)(nk + 1)) * 512 + (row & 15) * 8;
  float acc[16];
#pragma unroll
  for (int r = 0; r < 16; ++r) acc[r] = 0.f;
  int nseg = K >> 3;
  for (int seg = lane; seg < nseg; seg += 64) {
    uint4 xv = *(const uint4*)(xp + (seg >> 2) * 512 + (seg & 3) * 128);
    float x0 = bflo(xv.x), x1 = bfhi(xv.x), x2 = bflo(xv.y), x3 = bfhi(xv.y);
    float x4 = bflo(xv.z), x5 = bfhi(xv.z), x6 = bflo(xv.w), x7 = bfhi(xv.w);
    int k = seg * 8;
#pragma unroll
    for (int r = 0; r < 16; ++r) {
      const float4* ar = (const float4*)(A + (long long)r * K + k);
      float4 a0 = ar[0], a1 = ar[1];
      acc[r] += x0 * a0.x + x1 * a0.y + x2 * a0.z + x3 * a0.w
              + x4 * a1.x + x5 * a1.y + x6 * a1.z + x7 * a1.w;
    }
  }
#pragma unroll
  for (int r = 0; r < 16; ++r) {
    float v = acc[r];
#pragma unroll
    for (int o = 32; o > 0; o >>= 1) v += __shfl_xor(v, o, 64);
    if (lane == r) T[row * 16 + r] = v;
  }
}

// ---------- async global->LDS staging helper ----------
typedef const __attribute__((address_space(1))) void* gas_ptr;
typedef __attribute__((address_space(3))) void* las_ptr;
__device__ __forceinline__ void stage_frag(const u16* __restrict__ g, u16* l) {
  __builtin_amdgcn_global_load_lds((gas_ptr)g, (las_ptr)l, 16, 0, 0);
}

// ---------- main GEMM: 256-row tiles, ring-3, counted vmcnt, padded strides ----------
template<int DO_GELU, int NFR>
__global__ __launch_bounds__(512, 2)
void gemm_qlora_kernel(const u16* __restrict__ Apk, const u16* __restrict__ Bpk,
                       const float* __restrict__ bias, const float* __restrict__ T,
                       const float* __restrict__ Bl, void* __restrict__ outp,
                       int M, int N, int K) {
  constexpr int BN  = NFR * 16;        // 256 or 128
  constexpr int TF  = 16 + NFR;        // frags per window (32 or 24)
  constexpr int L   = TF / 8;          // gload_lds per wave per window (4 or 3)
  constexpr int WNT = NFR / 4;         // per-wave B frags (4 or 2)

  const int tid = threadIdx.x;
  const int wave = tid >> 6, lane = tid & 63;
  const int quad = lane >> 4, m16 = lane & 15;
  const int wrow = wave >> 2, wcol = wave & 3;   // 2x4 wave grid

  const int per = (M >> 8) >> 3;       // bm tiles per XCD (M/256/8)
  int j = blockIdx.x & 7, t = blockIdx.x >> 3;
  int bm = j * per + (t & (per - 1));
  int bn = t / per;

  const int nk = K >> 5;
  const size_t ms = (size_t)(nk + 1) * 512;   // PADDED frag-row stride (u16)

  __shared__ u16 lds[3][TF][512];      // ring-3

  const u16* gsrc[L];
#pragma unroll
  for (int i = 0; i < L; ++i) {
    int f = wave * L + i;
    gsrc[i] = (f < 16 ? Apk + (size_t)(bm * 16 + f) * ms
                      : Bpk + (size_t)(bn * NFR + (f - 16)) * ms) + lane * 8;
  }

  floatx4 acc[8][WNT] = {};

#pragma unroll
  for (int pt = 0; pt < 2; ++pt)
#pragma unroll
    for (int i = 0; i < L; ++i)
      stage_frag(gsrc[i] + (size_t)pt * 512, &lds[pt][wave * L + i][0]);
  if constexpr (L == 4) VMWAIT(4); else VMWAIT(3);   // window 0 resident
  BARRIER();

#define COMPUTE_TILE(CS)                                                        \
  {                                                                             \
    const u16* la = &lds[CS][wrow * 8][0] + (size_t)lane * 8;                   \
    const u16* lb = &lds[CS][16 + wcol * WNT][0] + (size_t)lane * 8;            \
    bf16x8 av[8], bv[WNT];                                                      \
    _Pragma("unroll")                                                           \
    for (int i = 0; i < 8; ++i) av[i] = *(const bf16x8*)(la + i * 512);         \
    _Pragma("unroll")                                                           \
    for (int i = 0; i < WNT; ++i) bv[i] = *(const bf16x8*)(lb + i * 512);       \
    _Pragma("unroll")                                                           \
    for (int mt = 0; mt < 8; ++mt)                                              \
      _Pragma("unroll")                                                         \
      for (int nt = 0; nt < WNT; ++nt)                                          \
        acc[mt][nt] = __builtin_amdgcn_mfma_f32_16x16x32_bf16(av[mt], bv[nt],   \
                                                              acc[mt][nt], 0, 0, 0); \
  }

  int cs = 0, ss = 2;                  // compute slot, stage slot
#pragma unroll 1
  for (int kt = 0; kt < nk - 2; ++kt) {
    const size_t ko = (size_t)(kt + 2) * 512;
#pragma unroll
    for (int i = 0; i < L; ++i)
      stage_frag(gsrc[i] + ko, &lds[ss][wave * L + i][0]);
    COMPUTE_TILE(cs);
    if constexpr (L == 4) VMWAIT(4); else VMWAIT(3);   // window kt+1 resident
    BARRIER();
    cs = (cs == 2) ? 0 : cs + 1;
    ss = (ss == 2) ? 0 : ss + 1;
  }
  COMPUTE_TILE(cs);
  VMWAIT(0);
  BARRIER();
  cs = (cs == 2) ? 0 : cs + 1;
  COMPUTE_TILE(cs);
#undef COMPUTE_TILE

  // epilogue: C/D layout row=(lane>>4)*4+reg, col=lane&15
  const float* Trow = T + (size_t)bm * 256 * 16;
  const float* Blrow = Bl + (size_t)bn * BN * 16;
  const size_t nk2p = (size_t)(N >> 5) + 1;   // padded chunk stride of NEXT gemm's input
#pragma unroll
  for (int mt = 0; mt < 8; ++mt) {
#pragma unroll
    for (int r = 0; r < 4; ++r) {
      int ml = wrow * 128 + mt * 16 + quad * 4 + r;
      size_t gm = (size_t)bm * 256 + ml;
      const float4* tv = (const float4*)(Trow + (size_t)ml * 16);
      float4 ta = tv[0], tb = tv[1], tc = tv[2], td = tv[3];
#pragma unroll
      for (int nt = 0; nt < WNT; ++nt) {
        int nl = wcol * (WNT * 16) + nt * 16 + m16;
        size_t gn = (size_t)bn * BN + nl;
        const float4* bv4 = (const float4*)(Blrow + (size_t)nl * 16);
        float4 ba = bv4[0], bb = bv4[1], bc = bv4[2], bd = bv4[3];
        float lora = ta.x * ba.x + ta.y * ba.y + ta.z * ba.z + ta.w * ba.w
                   + tb.x * bb.x + tb.y * bb.y + tb.z * bb.z + tb.w * bb.w
                   + tc.x * bc.x + tc.y * bc.y + tc.z * bc.z + tc.w * bc.w
                   + td.x * bd.x + td.y * bd.y + td.z * bd.z + td.w * bd.w;
        float v = acc[mt][nt][r] + bias[gn] + LORA_SCALING * lora;
        if (DO_GELU) {
          float g = 0.5f * v * (1.0f + erff(v * 0.70710678118654752f));
          size_t dst = ((gm >> 4) * nk2p + (gn >> 5)) * 512
                     + (gm & 15) * 8 + (((gn >> 3) & 3) << 7) + (gn & 7);
          ((u16*)outp)[dst] = f2bf(g);
        } else {
          ((float*)outp)[gm * (size_t)N + gn] = v;
        }
      }
    }
  }
}

// ---------- ABLATION kernel (diagnostic; writes checksum to scratch) ----------
// GEMM2 geometry (NFR=8). ABL=1: full loop, no epilogue. ABL=2: staging only.
// ABL=3: compute only (no staging loads). Values kept live per rule #17.
template<int ABL>
__global__ __launch_bounds__(512, 2)
void gemm_abl_kernel(const u16* __restrict__ Apk, const u16* __restrict__ Bpk,
                     u16* __restrict__ scratch, int M, int N, int K) {
  constexpr int NFR = 8;
  constexpr int TF  = 16 + NFR;        // 24
  constexpr int L   = TF / 8;          // 3
  constexpr int WNT = NFR / 4;         // 2

  const int tid = threadIdx.x;
  const int wave = tid >> 6, lane = tid & 63;
  const int wrow = wave >> 2, wcol = wave & 3;

  const int per = (M >> 8) >> 3;
  int j = blockIdx.x & 7, t = blockIdx.x >> 3;
  int bm = j * per + (t & (per - 1));
  int bn = t / per;

  const int nk = K >> 5;
  const size_t ms = (size_t)(nk + 1) * 512;

  __shared__ u16 lds[3][TF][512];

  const u16* gsrc[L];
#pragma unroll
  for (int i = 0; i < L; ++i) {
    int f = wave * L + i;
    gsrc[i] = (f < 16 ? Apk + (size_t)(bm * 16 + f) * ms
                      : Bpk + (size_t)(bn * NFR + (f - 16)) * ms) + lane * 8;
  }

  floatx4 acc[8][WNT] = {};

#define COMPUTE_T(CS)                                                           \
  {                                                                             \
    const u16* la = &lds[CS][wrow * 8][0] + (size_t)lane * 8;                   \
    const u16* lb = &lds[CS][16 + wcol * WNT][0] + (size_t)lane * 8;            \
    bf16x8 av[8], bv[WNT];                                                      \
    _Pragma("unroll")                                                           \
    for (int i = 0; i < 8; ++i) av[i] = *(const bf16x8*)(la + i * 512);         \
    _Pragma("unroll")                                                           \
    for (int i = 0; i < WNT; ++i) bv[i] = *(const bf16x8*)(lb + i * 512);       \
    _Pragma("unroll")                                                           \
    for (int mt = 0; mt < 8; ++mt)                                              \
      _Pragma("unroll")                                                         \
      for (int nt = 0; nt < WNT; ++nt)                                          \
        acc[mt][nt] = __builtin_amdgcn_mfma_f32_16x16x32_bf16(av[mt], bv[nt],   \
                                                              acc[mt][nt], 0, 0, 0); \
  }

  if constexpr (ABL == 3) {
    // one staging round to init slot 0; then pure ds_read+MFMA+barrier loop
#pragma unroll
    for (int i = 0; i < L; ++i) stage_frag(gsrc[i], &lds[0][wave * L + i][0]);
    VMWAIT(0);
    BARRIER();
    int cs = 0;
#pragma unroll 1
    for (int kt = 0; kt < nk; ++kt) {
      COMPUTE_T(cs);
      BARRIER();
      cs = (cs == 2) ? 0 : cs + 1;
    }
  } else {
#pragma unroll
    for (int pt = 0; pt < 2; ++pt)
#pragma unroll
      for (int i = 0; i < L; ++i)
        stage_frag(gsrc[i] + (size_t)pt * 512, &lds[pt][wave * L + i][0]);
    VMWAIT(3);
    BARRIER();
    int cs = 0, ss = 2;
#pragma unroll 1
    for (int kt = 0; kt < nk - 2; ++kt) {
      const size_t ko = (size_t)(kt + 2) * 512;
#pragma unroll
      for (int i = 0; i < L; ++i)
        stage_frag(gsrc[i] + ko, &lds[ss][wave * L + i][0]);
      if constexpr (ABL != 2) COMPUTE_T(cs);
      VMWAIT(3);
      BARRIER();
      cs = (cs == 2) ? 0 : cs + 1;
      ss = (ss == 2) ? 0 : ss + 1;
    }
    if constexpr (ABL != 2) COMPUTE_T(cs);
    VMWAIT(0);
    BARRIER();
    cs = (cs == 2) ? 0 : cs + 1;
    if constexpr (ABL != 2) COMPUTE_T(cs);
  }
#undef COMPUTE_T

  if constexpr (ABL == 2) {
    u16 v = lds[0][wave * L][lane * 8];      // keep staged data observed
    scratch[(size_t)blockIdx.x * 512 + tid] = v;
  } else {
    float s = 0.f;
#pragma unroll
    for (int mt = 0; mt < 8; ++mt)
#pragma unroll
      for (int nt = 0; nt < WNT; ++nt)
#pragma unroll
        for (int r = 0; r < 4; ++r) s += acc[mt][nt][r];
    scratch[(size_t)blockIdx.x * 512 + tid] = f2bf(s);   // keep all MFMAs live
  }
}

// ---------- launch ----------
extern "C" void kernel_launch(void* const* d_in, const int* in_sizes, int n_in,
                              void* d_out, int out_size, void* d_ws, size_t ws_size,
                              hipStream_t stream) {
  const float* x    = (const float*)d_in[0];
  const float* W_fc = (const float*)d_in[1];
  const float* b_fc = (const float*)d_in[2];
  const float* A_fc = (const float*)d_in[3];
  const float* B_fc = (const float*)d_in[4];
  const float* W_pr = (const float*)d_in[5];
  const float* b_pr = (const float*)d_in[6];
  const float* A_pr = (const float*)d_in[7];
  const float* B_pr = (const float*)d_in[8];
  float* out = (float*)d_out;

  const int F = in_sizes[2];                 // 4096
  const int D = in_sizes[6];                 // 1024
  const int M = in_sizes[0] / D;             // 8192
  int dsh = 0; while ((1 << dsh) < D) ++dsh;
  int fsh = 0; while ((1 << fsh) < F) ++fsh;

  const size_t PAD = 1 << 17;                // per-buffer tail pad (prefetch overrun)
  const int nkD = D >> 5, nkF = F >> 5;      // chunks per frag-row
  const size_t szfc = (size_t)(F / 16) * (nkD + 1) * 512 + PAD;
  const size_t szpr = (size_t)(D / 16) * (nkF + 1) * 512 + PAD;
  const size_t szx  = (size_t)(M / 16) * (nkD + 1) * 512 + PAD;
  const size_t szg  = (size_t)(M / 16) * (nkF + 1) * 512 + PAD;

  char* ws = (char*)d_ws;
  unsigned* amax = (unsigned*)ws;
  u16* wq_fc = (u16*)(ws + 1024);
  u16* wq_pr = wq_fc + szfc;
  u16* xbf   = wq_pr + szpr;
  u16* gbf   = xbf + szx;
  float* t1  = (float*)(gbf + szg);
  float* t2  = t1 + (size_t)M * 16;
  u16* ablsc = (u16*)(t2 + (size_t)M * 16);  // 256KB diagnostic scratch

  long long wfd4 = (long long)F * D / 4;
  long long wfd8 = (long long)F * D / 8;
  long long xch  = (long long)M * D / 8;

  zero_kernel<<<1, 64, 0, stream>>>(amax);
  absmax2_kernel<<<2048, 256, 0, stream>>>(W_fc, W_pr, wfd4, amax);
  pack_all_kernel<<<2048, 256, 0, stream>>>(W_fc, W_pr, x, amax, wq_fc, wq_pr, xbf,
                                            wfd8, wfd8, xch, dsh - 3, fsh - 3, dsh - 3);
  lora_t_kernel<<<M / 4, 256, 0, stream>>>(xbf, A_fc, t1, D);
  gemm_qlora_kernel<1, 16><<<dim3((M / 256) * (F / 256)), 512, 0, stream>>>(
      xbf, wq_fc, b_fc, t1, B_fc, (void*)gbf, M, F, D);
  lora_t_kernel<<<M / 4, 256, 0, stream>>>(gbf, A_pr, t2, F);
  gemm_qlora_kernel<0, 8><<<dim3((M / 256) * (D / 128)), 512, 0, stream>>>(
      gbf, wq_pr, b_pr, t2, B_pr, (void*)out, M, D, F);

  // ---- diagnostic ablations (GEMM2 geometry, scratch output) ----
  gemm_abl_kernel<1><<<dim3((M / 256) * (D / 128)), 512, 0, stream>>>(gbf, wq_pr, ablsc, M, D, F);
  gemm_abl_kernel<2><<<dim3((M / 256) * (D / 128)), 512, 0, stream>>>(gbf, wq_pr, ablsc, M, D, F);
  gemm_abl_kernel<3><<<dim3((M / 256) * (D / 128)), 512, 0, stream>>>(gbf, wq_pr, ablsc, M, D, F);
}

// Round 21
// 442.946 us; speedup vs baseline: 1.9308x; 1.9308x over previous
//
#include <hip/hip_runtime.h>
#include <hip/hip_bf16.h>
#include <math.h>

typedef unsigned short u16;
typedef __bf16 bf16x8 __attribute__((ext_vector_type(8)));
typedef float floatx4 __attribute__((ext_vector_type(4)));

// R17 ablation: 3 abl dispatches summed to ~148us vs 285us/GEMM -> the
// EPILOGUE (384-640 T/Bl loads + serial 16-FMA LoRA chain per thread) was
// the invariant bottleneck across R0-R15, not the main loop.
// Fix: fold LoRA into K. C = X Wq^T + T (2*Bl)^T, so append one 32-wide
// K-window: A cols [T | 0] (bf16), B cols [2*Bl | 0]. The R13 padded layout's
// spare chunk nk per frag-row IS the slot. Epilogue = acc + bias (+gelu).

// counted waits + raw barrier (T4): never drain vmcnt in the main loop.
#define VMWAIT(n) asm volatile("s_waitcnt vmcnt(" #n ")" ::: "memory")
#define BARRIER() asm volatile("s_barrier" ::: "memory")

// ---------- helpers ----------
__device__ __forceinline__ u16 f2bf(float f) {
  unsigned u = __float_as_uint(f);
  u += 0x7fffu + ((u >> 16) & 1u);   // round-to-nearest-even
  return (u16)(u >> 16);
}
__device__ __forceinline__ float bflo(unsigned u) { return __uint_as_float(u << 16); }
__device__ __forceinline__ float bfhi(unsigned u) { return __uint_as_float(u & 0xffff0000u); }

// ---------- zero amax slots (ws poisoned 0xAA each launch) ----------
__global__ void zero_kernel(unsigned* amax) {
  if (threadIdx.x < 2) amax[threadIdx.x] = 0u;
}

// ---------- fused absmax of both weight tensors ----------
__global__ void absmax2_kernel(const float* __restrict__ wa, const float* __restrict__ wb,
                               long long n4, unsigned* __restrict__ out) {
  int which = blockIdx.x & 1;
  const float* w = which ? wb : wa;
  long long i = (long long)(blockIdx.x >> 1) * blockDim.x + threadIdx.x;
  long long stride = (long long)(gridDim.x >> 1) * blockDim.x;
  float m = 0.f;
  for (; i < n4; i += stride) {
    float4 v = ((const float4*)w)[i];
    m = fmaxf(m, fmaxf(fmaxf(fabsf(v.x), fabsf(v.y)), fmaxf(fabsf(v.z), fabsf(v.w))));
  }
#pragma unroll
  for (int o = 32; o > 0; o >>= 1) m = fmaxf(m, __shfl_xor(m, o, 64));
  __shared__ float sm[4];
  int lane = threadIdx.x & 63, wv = threadIdx.x >> 6;
  if (lane == 0) sm[wv] = m;
  __syncthreads();
  if (threadIdx.x == 0) {
    float mm = fmaxf(fmaxf(sm[0], sm[1]), fmaxf(sm[2], sm[3]));
    atomicMax(out + which, __float_as_uint(mm));   // nonneg: uint order == float order
  }
}

// ---------- packing, dst-major with padded row stride ----------
// Data chunks 0..nk-1 per frag-row; chunk nk reserved for the LoRA window.
__device__ __forceinline__ void pack_q(const float* __restrict__ w, u16* __restrict__ dst,
                                       long long d, int nkc, int kc3, float inv, float scale) {
  int l = (int)(d & 63);
  long long frag = d >> 6;
  long long mb = frag / nkc, kc = frag % nkc;
  long long m = mb * 16 + (l & 15);
  long long k8 = kc * 4 + (l >> 4);
  const float4* s = (const float4*)(w + ((m << kc3) + k8) * 8);
  float4 a = s[0], b = s[1];
  union { u16 h[8]; uint4 v; } o;
  o.h[0] = f2bf(fminf(fmaxf(rintf(a.x * inv), -128.f), 127.f) * scale);
  o.h[1] = f2bf(fminf(fmaxf(rintf(a.y * inv), -128.f), 127.f) * scale);
  o.h[2] = f2bf(fminf(fmaxf(rintf(a.z * inv), -128.f), 127.f) * scale);
  o.h[3] = f2bf(fminf(fmaxf(rintf(a.w * inv), -128.f), 127.f) * scale);
  o.h[4] = f2bf(fminf(fmaxf(rintf(b.x * inv), -128.f), 127.f) * scale);
  o.h[5] = f2bf(fminf(fmaxf(rintf(b.y * inv), -128.f), 127.f) * scale);
  o.h[6] = f2bf(fminf(fmaxf(rintf(b.z * inv), -128.f), 127.f) * scale);
  o.h[7] = f2bf(fminf(fmaxf(rintf(b.w * inv), -128.f), 127.f) * scale);
  ((uint4*)dst)[(mb * (nkc + 1) + kc) * 64 + l] = o.v;
}
__device__ __forceinline__ void pack_c(const float* __restrict__ x, u16* __restrict__ dst,
                                       long long d, int nkc, int kc3) {
  int l = (int)(d & 63);
  long long frag = d >> 6;
  long long mb = frag / nkc, kc = frag % nkc;
  long long m = mb * 16 + (l & 15);
  long long k8 = kc * 4 + (l >> 4);
  const float4* s = (const float4*)(x + ((m << kc3) + k8) * 8);
  float4 a = s[0], b = s[1];
  union { u16 h[8]; uint4 v; } o;
  o.h[0] = f2bf(a.x); o.h[1] = f2bf(a.y); o.h[2] = f2bf(a.z); o.h[3] = f2bf(a.w);
  o.h[4] = f2bf(b.x); o.h[5] = f2bf(b.y); o.h[6] = f2bf(b.z); o.h[7] = f2bf(b.w);
  ((uint4*)dst)[(mb * (nkc + 1) + kc) * 64 + l] = o.v;
}

__global__ void pack_all_kernel(const float* __restrict__ wfc, const float* __restrict__ wpr,
                                const float* __restrict__ x, const unsigned* __restrict__ amax,
                                u16* __restrict__ qfc, u16* __restrict__ qpr, u16* __restrict__ xb,
                                long long nfc, long long npr, long long nx, int kfc, int kpr, int kx) {
  float am0 = __uint_as_float(amax[0]);
  float am1 = __uint_as_float(amax[1]);
  float sc0 = am0 * (1.0f / 127.0f), in0 = 127.0f / am0;
  float sc1 = am1 * (1.0f / 127.0f), in1 = 127.0f / am1;
  long long i = (long long)blockIdx.x * blockDim.x + threadIdx.x;
  long long stride = (long long)gridDim.x * blockDim.x;
  long long tot = nfc + npr + nx;
  for (; i < tot; i += stride) {
    if (i < nfc)            pack_q(wfc, qfc, i, 1 << (kfc - 2), kfc, in0, sc0);
    else if (i < nfc + npr) pack_q(wpr, qpr, i - nfc, 1 << (kpr - 2), kpr, in1, sc1);
    else                    pack_c(x, xb, i - nfc - npr, 1 << (kx - 2), kx);
  }
}

// ---------- pack SCALING*B (rows x 16 fp32) into weight buffer's LoRA chunk ----------
// dst frag: lane l = row (l&15), cols (l>>4)*8..+7; cols 0-15 = 2*B, 16-31 = 0.
__global__ void pack_lorab_kernel(const float* __restrict__ Bl, u16* __restrict__ dst,
                                  int rows, int nk) {
  int i = blockIdx.x * blockDim.x + threadIdx.x;
  if (i >= rows * 32) return;
  int row = i >> 5, c = i & 31;
  u16 v = (c < 16) ? f2bf(2.0f * Bl[(size_t)row * 16 + c]) : (u16)0;
  dst[(((size_t)(row >> 4) * (nk + 1)) + nk) * 512 + ((c >> 3) * 16 + (row & 15)) * 8 + (c & 7)] = v;
}

// ---------- LoRA T = X @ A^T, written as bf16 DIRECTLY into X's LoRA chunk ----------
__global__ void lora_t_kernel(u16* __restrict__ X, const float* __restrict__ A, int K) {
  int wv = threadIdx.x >> 6, lane = threadIdx.x & 63;
  long long row = (long long)blockIdx.x * 4 + wv;
  int nk = K >> 5;
  const u16* xp = X + ((row >> 4) * (long long)(nk + 1)) * 512 + (row & 15) * 8;
  float acc[16];
#pragma unroll
  for (int r = 0; r < 16; ++r) acc[r] = 0.f;
  int nseg = K >> 3;
  for (int seg = lane; seg < nseg; seg += 64) {
    uint4 xv = *(const uint4*)(xp + (seg >> 2) * 512 + (seg & 3) * 128);
    float x0 = bflo(xv.x), x1 = bfhi(xv.x), x2 = bflo(xv.y), x3 = bfhi(xv.y);
    float x4 = bflo(xv.z), x5 = bfhi(xv.z), x6 = bflo(xv.w), x7 = bfhi(xv.w);
    int k = seg * 8;
#pragma unroll
    for (int r = 0; r < 16; ++r) {
      const float4* ar = (const float4*)(A + (long long)r * K + k);
      float4 a0 = ar[0], a1 = ar[1];
      acc[r] += x0 * a0.x + x1 * a0.y + x2 * a0.z + x3 * a0.w
              + x4 * a1.x + x5 * a1.y + x6 * a1.z + x7 * a1.w;
    }
  }
  // write T[row][r] as bf16 into chunk nk of frag-row row>>4; zero cols 16-31
  u16* dstc = X + (((row >> 4) * (long long)(nk + 1)) + nk) * 512;
#pragma unroll
  for (int r = 0; r < 16; ++r) {
    float v = acc[r];
#pragma unroll
    for (int o = 32; o > 0; o >>= 1) v += __shfl_xor(v, o, 64);
    if (lane == r) dstc[((r >> 3) * 16 + (int)(row & 15)) * 8 + (r & 7)] = f2bf(v);
  }
  if (lane >= 16 && lane < 32)
    dstc[((lane >> 3) * 16 + (int)(row & 15)) * 8 + (lane & 7)] = 0;
}

// ---------- async global->LDS staging helper ----------
typedef const __attribute__((address_space(1))) void* gas_ptr;
typedef __attribute__((address_space(3))) void* las_ptr;
__device__ __forceinline__ void stage_frag(const u16* __restrict__ g, u16* l) {
  __builtin_amdgcn_global_load_lds((gas_ptr)g, (las_ptr)l, 16, 0, 0);
}

// ---------- main GEMM: 256-row tiles, ring-3, counted vmcnt, LoRA folded into K ----------
// Windows 0..nk-1 = data, window nk = LoRA rank-16 correction (zero-padded to 32).
// Epilogue is now just acc + bias (+gelu) + store.
template<int DO_GELU, int NFR>
__global__ __launch_bounds__(512, 2)
void gemm_qlora_kernel(const u16* __restrict__ Apk, const u16* __restrict__ Bpk,
                       const float* __restrict__ bias, void* __restrict__ outp,
                       int M, int N, int K) {
  constexpr int BN  = NFR * 16;        // 256 or 128
  constexpr int TF  = 16 + NFR;        // frags per window (32 or 24)
  constexpr int L   = TF / 8;          // gload_lds per wave per window (4 or 3)
  constexpr int WNT = NFR / 4;         // per-wave B frags (4 or 2)

  const int tid = threadIdx.x;
  const int wave = tid >> 6, lane = tid & 63;
  const int quad = lane >> 4, m16 = lane & 15;
  const int wrow = wave >> 2, wcol = wave & 3;   // 2x4 wave grid

  const int per = (M >> 8) >> 3;       // bm tiles per XCD (M/256/8)
  int j = blockIdx.x & 7, t = blockIdx.x >> 3;
  int bm = j * per + (t & (per - 1));
  int bn = t / per;

  const int nkk = (K >> 5) + 1;        // data windows + LoRA window
  const size_t ms = (size_t)nkk * 512; // frag-row stride (u16)

  __shared__ u16 lds[3][TF][512];      // ring-3

  const u16* gsrc[L];
#pragma unroll
  for (int i = 0; i < L; ++i) {
    int f = wave * L + i;
    gsrc[i] = (f < 16 ? Apk + (size_t)(bm * 16 + f) * ms
                      : Bpk + (size_t)(bn * NFR + (f - 16)) * ms) + lane * 8;
  }

  floatx4 acc[8][WNT] = {};

#pragma unroll
  for (int pt = 0; pt < 2; ++pt)
#pragma unroll
    for (int i = 0; i < L; ++i)
      stage_frag(gsrc[i] + (size_t)pt * 512, &lds[pt][wave * L + i][0]);
  if constexpr (L == 4) VMWAIT(4); else VMWAIT(3);   // window 0 resident
  BARRIER();

#define COMPUTE_TILE(CS)                                                        \
  {                                                                             \
    const u16* la = &lds[CS][wrow * 8][0] + (size_t)lane * 8;                   \
    const u16* lb = &lds[CS][16 + wcol * WNT][0] + (size_t)lane * 8;            \
    bf16x8 av[8], bv[WNT];                                                      \
    _Pragma("unroll")                                                           \
    for (int i = 0; i < 8; ++i) av[i] = *(const bf16x8*)(la + i * 512);         \
    _Pragma("unroll")                                                           \
    for (int i = 0; i < WNT; ++i) bv[i] = *(const bf16x8*)(lb + i * 512);       \
    _Pragma("unroll")                                                           \
    for (int mt = 0; mt < 8; ++mt)                                              \
      _Pragma("unroll")                                                         \
      for (int nt = 0; nt < WNT; ++nt)                                          \
        acc[mt][nt] = __builtin_amdgcn_mfma_f32_16x16x32_bf16(av[mt], bv[nt],   \
                                                              acc[mt][nt], 0, 0, 0); \
  }

  int cs = 0, ss = 2;                  // compute slot, stage slot
#pragma unroll 1
  for (int kt = 0; kt < nkk - 2; ++kt) {
    const size_t ko = (size_t)(kt + 2) * 512;
#pragma unroll
    for (int i = 0; i < L; ++i)
      stage_frag(gsrc[i] + ko, &lds[ss][wave * L + i][0]);
    COMPUTE_TILE(cs);
    if constexpr (L == 4) VMWAIT(4); else VMWAIT(3);   // window kt+1 resident
    BARRIER();
    cs = (cs == 2) ? 0 : cs + 1;
    ss = (ss == 2) ? 0 : ss + 1;
  }
  COMPUTE_TILE(cs);
  VMWAIT(0);
  BARRIER();
  cs = (cs == 2) ? 0 : cs + 1;
  COMPUTE_TILE(cs);
#undef COMPUTE_TILE

  // epilogue: C/D layout row=(lane>>4)*4+reg, col=lane&15; LoRA already in acc
  const size_t nk2p = (size_t)(N >> 5) + 1;   // padded chunk stride of NEXT gemm's input
#pragma unroll
  for (int mt = 0; mt < 8; ++mt) {
#pragma unroll
    for (int r = 0; r < 4; ++r) {
      int ml = wrow * 128 + mt * 16 + quad * 4 + r;
      size_t gm = (size_t)bm * 256 + ml;
#pragma unroll
      for (int nt = 0; nt < WNT; ++nt) {
        int nl = wcol * (WNT * 16) + nt * 16 + m16;
        size_t gn = (size_t)bn * BN + nl;
        float v = acc[mt][nt][r] + bias[gn];
        if (DO_GELU) {
          float g = 0.5f * v * (1.0f + erff(v * 0.70710678118654752f));
          size_t dst = ((gm >> 4) * nk2p + (gn >> 5)) * 512
                     + (gm & 15) * 8 + (((gn >> 3) & 3) << 7) + (gn & 7);
          ((u16*)outp)[dst] = f2bf(g);
        } else {
          ((float*)outp)[gm * (size_t)N + gn] = v;
        }
      }
    }
  }
}

// ---------- launch ----------
extern "C" void kernel_launch(void* const* d_in, const int* in_sizes, int n_in,
                              void* d_out, int out_size, void* d_ws, size_t ws_size,
                              hipStream_t stream) {
  const float* x    = (const float*)d_in[0];
  const float* W_fc = (const float*)d_in[1];
  const float* b_fc = (const float*)d_in[2];
  const float* A_fc = (const float*)d_in[3];
  const float* B_fc = (const float*)d_in[4];
  const float* W_pr = (const float*)d_in[5];
  const float* b_pr = (const float*)d_in[6];
  const float* A_pr = (const float*)d_in[7];
  const float* B_pr = (const float*)d_in[8];
  float* out = (float*)d_out;

  const int F = in_sizes[2];                 // 4096
  const int D = in_sizes[6];                 // 1024
  const int M = in_sizes[0] / D;             // 8192
  int dsh = 0; while ((1 << dsh) < D) ++dsh;
  int fsh = 0; while ((1 << fsh) < F) ++fsh;

  const size_t PAD = 1 << 17;                // per-buffer tail pad
  const int nkD = D >> 5, nkF = F >> 5;      // data chunks per frag-row
  const size_t szfc = (size_t)(F / 16) * (nkD + 1) * 512 + PAD;
  const size_t szpr = (size_t)(D / 16) * (nkF + 1) * 512 + PAD;
  const size_t szx  = (size_t)(M / 16) * (nkD + 1) * 512 + PAD;
  const size_t szg  = (size_t)(M / 16) * (nkF + 1) * 512 + PAD;

  char* ws = (char*)d_ws;
  unsigned* amax = (unsigned*)ws;
  u16* wq_fc = (u16*)(ws + 1024);
  u16* wq_pr = wq_fc + szfc;
  u16* xbf   = wq_pr + szpr;
  u16* gbf   = xbf + szx;

  long long wfd4 = (long long)F * D / 4;
  long long wfd8 = (long long)F * D / 8;
  long long xch  = (long long)M * D / 8;

  zero_kernel<<<1, 64, 0, stream>>>(amax);
  absmax2_kernel<<<2048, 256, 0, stream>>>(W_fc, W_pr, wfd4, amax);
  pack_all_kernel<<<2048, 256, 0, stream>>>(W_fc, W_pr, x, amax, wq_fc, wq_pr, xbf,
                                            wfd8, wfd8, xch, dsh - 3, fsh - 3, dsh - 3);
  // pack 2*B into weight buffers' LoRA chunks
  pack_lorab_kernel<<<(F * 32 + 255) / 256, 256, 0, stream>>>(B_fc, wq_fc, F, nkD);
  pack_lorab_kernel<<<(D * 32 + 255) / 256, 256, 0, stream>>>(B_pr, wq_pr, D, nkF);
  // T1 = X A_fc^T -> xbf LoRA chunk
  lora_t_kernel<<<M / 4, 256, 0, stream>>>(xbf, A_fc, D);
  // GEMM1: 256x256 tiles, grid 512
  gemm_qlora_kernel<1, 16><<<dim3((M / 256) * (F / 256)), 512, 0, stream>>>(
      xbf, wq_fc, b_fc, (void*)gbf, M, F, D);
  // T2 = H A_pr^T -> gbf LoRA chunk
  lora_t_kernel<<<M / 4, 256, 0, stream>>>(gbf, A_pr, F);
  // GEMM2: 256x128 tiles, grid 256
  gemm_qlora_kernel<0, 8><<<dim3((M / 256) * (D / 128)), 512, 0, stream>>>(
      gbf, wq_pr, b_pr, (void*)out, M, D, F);
}